// Round 14
// baseline (67.553 us; speedup 1.0000x reference)
//
#include <hip/hip_runtime.h>

#define D      64
#define K      512
#define Q_OFF  0            // out[0 .. 8388607]   quantized_ste (NCHW)
#define L_OFF  8388608      // out[8388608]        commitment loss
#define I_OFF  8388609      // out[8388609 .. ]    indices (131072)

// ws layout (floats)
#define WS_ET    0          // 512*64 transposed embeddings (fp32, exact)
#define WS_EN    32768      // 512 ||e||^2
#define WS_ENH   33280      // 512 0.5*||e||^2
#define WS_PART  33792      // 4096 partial loss sums
#define WS_BH    40960      // hi B-fragment table, 16384 floats (64 KB)
#define WS_BL    57344      // lo B-fragment table, 16384 floats (64 KB)

// packed fixed-point selection constants
#define SEL_SCALE 16384.0f              // 2^14: resolution 6.1e-5
#define SEL_BIAS  (160.0f * 16384.0f)   // acc in (-65, 312) -> positive, < 2^23

typedef __attribute__((ext_vector_type(8))) short short8;   // 8 bf16 = 4 VGPRs
typedef __attribute__((ext_vector_type(4))) float f32x4;

static __device__ __forceinline__ unsigned short f2bf(float f) {
    unsigned u = __float_as_uint(f);
    u += 0x7fffu + ((u >> 16) & 1u);       // RTN-even
    return (unsigned short)(u >> 16);
}
static __device__ __forceinline__ float bf2f(unsigned short h) {
    return __uint_as_float(((unsigned)h) << 16);
}

// async global->LDS, 16 B per lane, linear layout
__device__ __forceinline__ void gload_lds16(const float* g, float* l) {
    __builtin_amdgcn_global_load_lds(
        (const __attribute__((address_space(1))) unsigned int*)g,
        (__attribute__((address_space(3))) unsigned int*)l, 16, 0, 0);
}

// ---------------------------------------------------------------- prep ----
__global__ __launch_bounds__(256) void vq_prep(const float* __restrict__ E,
                                               float* __restrict__ ws) {
    int g = blockIdx.x * 256 + threadIdx.x;   // 0..2047 = (t, lane)
    int t = g >> 6, lane = g & 63;
    int col = lane & 15, kg = lane >> 4;
    int code = t * 16 + col;
    short8* bhp = (short8*)(ws + WS_BH);
    short8* blp = (short8*)(ws + WS_BL);
#pragma unroll
    for (int s = 0; s < 2; ++s) {
        short8 h, l;
#pragma unroll
        for (int j = 0; j < 8; ++j) {
            int k = s * 32 + kg * 8 + j;
            float v = -E[k * K + code];
            unsigned short hb = f2bf(v);
            h[j] = (short)hb;
            l[j] = (short)f2bf(v - bf2f(hb));
        }
        bhp[(t * 2 + s) * 64 + lane] = h;
        blp[(t * 2 + s) * 64 + lane] = l;
    }
    if (g < K) {
        float nsq = 0.f;
#pragma unroll 8
        for (int d = 0; d < D; ++d) {
            float v = E[d * K + g];
            ws[WS_ET + g * D + d] = v;
            nsq = fmaf(v, v, nsq);
        }
        ws[WS_EN + g]  = nsq;
        ws[WS_ENH + g] = 0.5f * nsq;
    }
}

// --------------------------------------------------------------- fused ----
// Dist part = r13 verbatim (proven): 4096 blocks x 2 waves, wave owns 16
// pixels x 512 codes, 3-pass split-bf16 MFMA, packed fixed-point top-2.
// Epilogue restructured: 8 lanes per pixel (dim-octets) -> e-row loads are
// 32 B contiguous per lane (8 rows/instr, not 64), dots via width-8 shfl
// butterfly, no LDS dot exchange. 2 passes x 16 pixels.
__global__ __launch_bounds__(128, 8) void vq_fused(const float* __restrict__ x,
                                                   float* __restrict__ ws,
                                                   float* __restrict__ out,
                                                   float* __restrict__ partial) {
    __shared__ float sbuf[2][1024];           // 2 x 4 KB: hi [0,512), lo [512,1024)
    __shared__ unsigned sc[32];               // candidate pairs per pixel
    __shared__ float wsum2[2];

    const int tid = threadIdx.x, w = tid >> 6, lane = tid & 63;
    const int col = lane & 15, rowg = lane >> 4;
    const int pixw = blockIdx.x * 32 + w * 16;

    const float* bh    = ws + WS_BH;          // hi table (512 f/tile)
    const float* bl    = ws + WS_BL;          // lo table
    const float* enh_g = ws + WS_ENH;

    // stage chunk 0 into buffer 0
    gload_lds16(bh + tid * 4, sbuf[0] + tid * 4);
    gload_lds16(bl + tid * 4, sbuf[0] + 512 + tid * 4);

    // ---- load x fragment and split to bf16 hi/lo: A[s]
    short8 ah[2], al[2];
    {
        int pix = pixw + col;
        const float* xp = x + ((size_t)(pix >> 12) << 18) + (pix & 4095);
#pragma unroll
        for (int s = 0; s < 2; ++s) {
            short8 h, l;
#pragma unroll
            for (int j = 0; j < 8; ++j) {
                float v = xp[(size_t)(s * 32 + rowg * 8 + j) << 12];
                unsigned short hb = f2bf(v);
                h[j] = (short)hb;
                l[j] = (short)f2bf(v - bf2f(hb));
            }
            ah[s] = h; al[s] = l;
        }
    }

    unsigned m1[4], m2[4];
#pragma unroll
    for (int r = 0; r < 4; ++r) { m1[r] = 0xFFFFFFFFu; m2[r] = 0xFFFFFFFFu; }

    __syncthreads();                           // chunk 0 staged

    for (int c = 0; c < 32; ++c) {
        if (c + 1 < 32) {
            const float* sh = bh + (c + 1) * 512;
            const float* sl = bl + (c + 1) * 512;
            float* db = sbuf[(c + 1) & 1];
            gload_lds16(sh + tid * 4, db + tid * 4);
            gload_lds16(sl + tid * 4, db + 512 + tid * 4);
        }

        const short8* sb = (const short8*)sbuf[c & 1];
        const float ev = enh_g[c * 16 + col];  // L1-hot 2KB table
        const unsigned codev = (unsigned)(c * 16 + col);

        short8 cbh0 = sb[lane];
        short8 cbh1 = sb[64 + lane];
        short8 cbl0 = sb[128 + lane];
        short8 cbl1 = sb[192 + lane];

        f32x4 acc = { ev, ev, ev, ev };
        __builtin_amdgcn_s_setprio(1);
        acc = __builtin_amdgcn_mfma_f32_16x16x32_bf16(ah[0], cbh0, acc, 0, 0, 0);
        acc = __builtin_amdgcn_mfma_f32_16x16x32_bf16(al[0], cbh0, acc, 0, 0, 0);
        acc = __builtin_amdgcn_mfma_f32_16x16x32_bf16(ah[0], cbl0, acc, 0, 0, 0);
        acc = __builtin_amdgcn_mfma_f32_16x16x32_bf16(ah[1], cbh1, acc, 0, 0, 0);
        acc = __builtin_amdgcn_mfma_f32_16x16x32_bf16(al[1], cbh1, acc, 0, 0, 0);
        acc = __builtin_amdgcn_mfma_f32_16x16x32_bf16(ah[1], cbl1, acc, 0, 0, 0);
        __builtin_amdgcn_s_setprio(0);

#pragma unroll
        for (int r = 0; r < 4; ++r) {
            unsigned p0 = (((unsigned)fmaf(acc[r], SEL_SCALE, SEL_BIAS)) << 9) + codev;
            m2[r] = min(m2[r], max(m1[r], p0));
            m1[r] = min(m1[r], p0);
        }

        __syncthreads();   // stage c+1 landed; both waves done with buf (c&1)
    }

    // cross-lane top-2 merge; park candidate pairs in LDS
#pragma unroll
    for (int r = 0; r < 4; ++r) {
        unsigned v1 = m1[r], v2 = m2[r];
#pragma unroll
        for (int m = 1; m < 16; m <<= 1) {
            unsigned o1 = (unsigned)__shfl_xor((int)v1, m, 16);
            unsigned o2 = (unsigned)__shfl_xor((int)v2, m, 16);
            v2 = min(max(v1, o1), min(v2, o2));
            v1 = min(v1, o1);
        }
        if (col == r)
            sc[w * 16 + rowg * 4 + r] = (v1 & 511u) | ((v2 & 511u) << 16);
    }
    __syncthreads();

    // ---------------- epilogue: 8 lanes/pixel, 2 passes x 16 pixels -------
    const float* ET = ws + WS_ET;
    const float* EN = ws + WS_EN;
    float lsum = 0.f;
#pragma unroll
    for (int pp = 0; pp < 2; ++pp) {
        const int pix = pp * 16 + w * 8 + (lane >> 3);   // pixel-in-block 0..31
        const int oct = lane & 7;                        // dim octet
        const int n   = blockIdx.x * 32 + pix;
        const int b   = n >> 12;
        const int hw  = n & 4095;

        unsigned pk = sc[pix];
        int c1 = (int)(pk & 0xffffu), c2 = (int)(pk >> 16);

        const float* xp2 = x + ((size_t)b << 18) + ((size_t)(oct * 8) << 12) + hw;
        float xv2[8];
#pragma unroll
        for (int j = 0; j < 8; ++j) xv2[j] = xp2[(size_t)j << 12];   // L3-warm

        const float4* e1 = (const float4*)(ET + (c1 << 6) + oct * 8);
        const float4* e2 = (const float4*)(ET + (c2 << 6) + oct * 8);
        float4 ea = e1[0], eb = e1[1], ec = e2[0], ed = e2[1];
        float d1p = 0.f, d2p = 0.f;
        d1p = fmaf(xv2[0], ea.x, d1p); d1p = fmaf(xv2[1], ea.y, d1p);
        d1p = fmaf(xv2[2], ea.z, d1p); d1p = fmaf(xv2[3], ea.w, d1p);
        d1p = fmaf(xv2[4], eb.x, d1p); d1p = fmaf(xv2[5], eb.y, d1p);
        d1p = fmaf(xv2[6], eb.z, d1p); d1p = fmaf(xv2[7], eb.w, d1p);
        d2p = fmaf(xv2[0], ec.x, d2p); d2p = fmaf(xv2[1], ec.y, d2p);
        d2p = fmaf(xv2[2], ec.z, d2p); d2p = fmaf(xv2[3], ec.w, d2p);
        d2p = fmaf(xv2[4], ed.x, d2p); d2p = fmaf(xv2[5], ed.y, d2p);
        d2p = fmaf(xv2[6], ed.z, d2p); d2p = fmaf(xv2[7], ed.w, d2p);

        // butterfly sum over the 8 octet lanes (deterministic, same in all 8)
#pragma unroll
        for (int mm = 1; mm < 8; mm <<= 1) {
            d1p += __shfl_xor(d1p, mm, 8);
            d2p += __shfl_xor(d2p, mm, 8);
        }
        float d1 = fmaf(-2.f, d1p, EN[c1]);
        float d2 = fmaf(-2.f, d2p, EN[c2]);
        bool sw = (d2 < d1) || (d2 == d1 && c2 < c1);   // np.argmin semantics
        int bestk = sw ? c2 : c1;

        if (oct == 0) out[I_OFF + n] = (float)bestk;

        const float4* eq = (const float4*)(ET + (bestk << 6) + oct * 8);
        float4 qa = eq[0], qb = eq[1];
        float qv[8] = { qa.x, qa.y, qa.z, qa.w, qb.x, qb.y, qb.z, qb.w };
        float* op = out + Q_OFF + ((size_t)b << 18) + ((size_t)(oct * 8) << 12) + hw;
#pragma unroll
        for (int j = 0; j < 8; ++j) {
            op[(size_t)j << 12] = qv[j];
            float diff = xv2[j] - qv[j];
            lsum = fmaf(diff, diff, lsum);
        }
    }

    // deterministic block loss reduction (2 waves)
#pragma unroll
    for (int off = 32; off > 0; off >>= 1)
        lsum += __shfl_down(lsum, off, 64);
    if ((tid & 63) == 0) wsum2[tid >> 6] = lsum;
    __syncthreads();
    if (tid == 0)
        partial[blockIdx.x] = wsum2[0] + wsum2[1];
}

// --------------------------------------------------------------- final ----
__global__ __launch_bounds__(256) void vq_final(const float* __restrict__ partial,
                                                float* __restrict__ out) {
    int t = threadIdx.x;
    float s = 0.f;
#pragma unroll
    for (int i = 0; i < 16; ++i) s += partial[t + 256 * i];   // 4096 partials
#pragma unroll
    for (int off = 32; off > 0; off >>= 1)
        s += __shfl_down(s, off, 64);
    __shared__ float wsum[4];
    if ((t & 63) == 0) wsum[t >> 6] = s;
    __syncthreads();
    if (t == 0)
        out[L_OFF] = ((wsum[0] + wsum[1]) + (wsum[2] + wsum[3])) * (1.f / 8388608.f);
}

extern "C" void kernel_launch(void* const* d_in, const int* in_sizes, int n_in,
                              void* d_out, int out_size, void* d_ws, size_t ws_size,
                              hipStream_t stream) {
    const float* x = (const float*)d_in[0];
    const float* E = (const float*)d_in[1];
    float* out = (float*)d_out;
    float* ws  = (float*)d_ws;

    hipLaunchKernelGGL(vq_prep,  dim3(8),    dim3(256), 0, stream, E, ws);
    hipLaunchKernelGGL(vq_fused, dim3(4096), dim3(128), 0, stream, x, ws, out, ws + WS_PART);
    hipLaunchKernelGGL(vq_final, dim3(1),    dim3(256), 0, stream, ws + WS_PART, out);
}